// Round 6
// baseline (1355.853 us; speedup 1.0000x reference)
//
#include <hip/hip_runtime.h>
#include <math.h>

// PredictorNoEgo: B=8192 T=8 E=256 M=20 FS=12
// Algebra: softmax over size-1 axis == 1 => ctx == v (q,k dead);
//          attn_out = emb @ (out_w[m] @ Wv[m])^T + (out_w[m]@bv[m] + out_b[m])
// R6: co-resident independent blocks per CU.
//  - mode_stack: 64-row tile, 1024 thr, acc[1]; LDS 68KB -> 2 blocks/CU
//    (8 waves/SIMD); one block's MFMA overlaps the other's VALU/barriers.
//  - lstm: phase-split (accA dead before accB) + c1 in LDS -> VGPR<=128,
//    2 blocks/CU. ELU via __expf (hw transcendental).

typedef float4 f4;
typedef unsigned int u32;
typedef unsigned short u16;
typedef __attribute__((ext_vector_type(16))) float f32x16;
typedef __attribute__((ext_vector_type(8)))  short s16x8;

__device__ __forceinline__ float sigm(float x){ return 1.0f/(1.0f + __expf(-x)); }
__device__ __forceinline__ float tanhfast(float x){ return 2.0f*sigm(2.0f*x) - 1.0f; }
__device__ __forceinline__ float eluf(float x){ return x > 0.f ? x : __expf(x) - 1.0f; }
__device__ __forceinline__ u16 f2bf(float x){
  u32 u = __float_as_uint(x);
  return (u16)((u + 0x7FFFu + ((u>>16)&1u)) >> 16);
}
__device__ __forceinline__ float bf2f(u16 h){ return __uint_as_float(((u32)h)<<16); }

// MFMA 32x32x16 bf16: A lane l: A[row=l&31][k=(l>>5)*8+j]; B lane l: B[k][col=l&31]
// C/D reg r: row=(r&3)+8*(r>>2)+4*(l>>5), col=l&31
// Fragment-linear W' (row-major W[C][K]): elem ((ct*(K/16)+ks)*64+l)*8+j
//   = W[ct*32+(l&31)][ks*16+(l>>5)*8+j]

#define LSTR 264  // LDS row stride in u16 (528B): 16B-aligned, bank-balanced

// ---------------------------------------------------------------------------
// W2c[m] = out_w[m] (256x256) @ in_proj_w[m,512:768,:] (256x256)   (fp32)
__global__ __launch_bounds__(256, 4)
void w2c_kernel(const float* __restrict__ out_w, const float* __restrict__ ipw,
                float* __restrict__ W2c)
{
  __shared__ float As[16][68];
  __shared__ float Bs2[16][68];
  const int tid = threadIdx.x;
  const int m = blockIdx.y;
  const int o0 = (blockIdx.x >> 2) * 64, e0 = (blockIdx.x & 3) * 64;
  const int trow = tid >> 4, tcol = tid & 15;
  const float* Ap = out_w + (size_t)m * 65536;
  const float* Bp = ipw + ((size_t)m * 768 + 512) * 256;
  float acc[16];
#pragma unroll
  for (int z = 0; z < 16; ++z) acc[z] = 0.f;
  for (int kb = 0; kb < 256; kb += 16) {
    { int row = tid >> 2, ko = (tid & 3) * 4;
      f4 v = *(const f4*)(Ap + (size_t)(o0+row)*256 + kb + ko);
      As[ko+0][row]=v.x; As[ko+1][row]=v.y; As[ko+2][row]=v.z; As[ko+3][row]=v.w; }
    { int k = tid >> 4, eo = (tid & 15) * 4;
      *(f4*)&Bs2[k][eo] = *(const f4*)(Bp + (size_t)(kb+k)*256 + e0 + eo); }
    __syncthreads();
#pragma unroll
    for (int k = 0; k < 16; ++k) {
      f4 a4 = *(const f4*)&As[k][trow*4];
      f4 b4 = *(const f4*)&Bs2[k][tcol*4];
      acc[0]+=a4.x*b4.x; acc[1]+=a4.x*b4.y; acc[2]+=a4.x*b4.z; acc[3]+=a4.x*b4.w;
      acc[4]+=a4.y*b4.x; acc[5]+=a4.y*b4.y; acc[6]+=a4.y*b4.z; acc[7]+=a4.y*b4.w;
      acc[8]+=a4.z*b4.x; acc[9]+=a4.z*b4.y; acc[10]+=a4.z*b4.z; acc[11]+=a4.z*b4.w;
      acc[12]+=a4.w*b4.x; acc[13]+=a4.w*b4.y; acc[14]+=a4.w*b4.z; acc[15]+=a4.w*b4.w;
    }
    __syncthreads();
  }
#pragma unroll
  for (int i = 0; i < 4; ++i)
    *(f4*)&W2c[((size_t)m*256 + o0 + trow*4 + i)*256 + e0 + tcol*4] =
        make_float4(acc[i*4+0], acc[i*4+1], acc[i*4+2], acc[i*4+3]);
}

__global__ void b2c_kernel(const float* __restrict__ out_w, const float* __restrict__ out_b,
                           const float* __restrict__ ipb, float* __restrict__ b2c)
{
  __shared__ float pb[256];
  const int m = blockIdx.x, o = threadIdx.x;
  pb[o] = ipb[(size_t)m*768 + 512 + o];
  __syncthreads();
  const float* wr = out_w + ((size_t)m*256 + o)*256;
  float acc = out_b[(size_t)m*256 + o];
  for (int f = 0; f < 256; f += 4) {
    f4 w = *(const f4*)&wr[f];
    acc += w.x*pb[f] + w.y*pb[f+1] + w.z*pb[f+2] + w.w*pb[f+3];
  }
  b2c[(size_t)m*256 + o] = acc;
}

// ---------------------------------------------------------------------------
// f32 row-major [C][K] -> fragment-linear bf16
__device__ __forceinline__ void cvt_seg(const float* __restrict__ src, u16* __restrict__ dst,
                                        int Creal, int lognks, int g)
{
  const int l = g & 63;
  const int cks = g >> 6;
  const int ks = cks & ((1 << lognks) - 1);
  const int ct = cks >> lognks;
  const int c = ct*32 + (l & 31);
  const int K = 16 << lognks;
  const int k = ks*16 + ((l >> 5) * 8);
  s16x8 r;
  if (c < Creal) {
    const float* s = src + (size_t)c * K + k;
    f4 v0 = *(const f4*)s;
    f4 v1 = *(const f4*)(s + 4);
    r[0]=(short)f2bf(v0.x); r[1]=(short)f2bf(v0.y); r[2]=(short)f2bf(v0.z); r[3]=(short)f2bf(v0.w);
    r[4]=(short)f2bf(v1.x); r[5]=(short)f2bf(v1.y); r[6]=(short)f2bf(v1.z); r[7]=(short)f2bf(v1.w);
  } else {
#pragma unroll
    for (int j = 0; j < 8; ++j) r[j] = 0;
  }
  *(s16x8*)(dst + (size_t)g * 8) = r;
}

__global__ __launch_bounds__(256)
void wcvt_all(const float* __restrict__ whh0, const float* __restrict__ wih1,
              const float* __restrict__ whh1, const float* __restrict__ W2c,
              const float* __restrict__ ffn1, const float* __restrict__ ffn2,
              const float* __restrict__ dec1, const float* __restrict__ dec2,
              const float* __restrict__ sc1,  u16* __restrict__ dst)
{
  int g = blockIdx.x * 256 + threadIdx.x;
  if      (g <  32768) cvt_seg(whh0, dst + 0,       1024, 4, g);
  else if (g <  65536) cvt_seg(wih1, dst + 262144,  1024, 4, g - 32768);
  else if (g <  98304) cvt_seg(whh1, dst + 524288,  1024, 4, g - 65536);
  else if (g < 262144) cvt_seg(W2c,  dst + 786432,  5120, 4, g - 98304);
  else if (g < 294912) cvt_seg(ffn1, dst + 2097152, 1024, 4, g - 262144);
  else if (g < 327680) cvt_seg(ffn2, dst + 2359296,  256, 6, g - 294912);
  else if (g < 344064) cvt_seg(dec1, dst + 2621440,  512, 4, g - 327680);
  else if (g < 346112) cvt_seg(dec2, dst + 2752512,   24, 5, g - 344064);
  else if (g < 350208) cvt_seg(sc1,  dst + 2768896,  128, 4, g - 346112);
}

// ---------------------------------------------------------------------------
// Fused LSTM: 256 blocks x 32 rows, 512 thr (8 waves), 2 blocks/CU.
// Phase-split: P1 accA=h0@whh0 ; E0 ; P2 accB=h0new@wih1 + h1old@whh1 ; E1.
// c0 in VGPR, c1 in LDS f32 (keeps peak VGPR <= 128).
__global__ __launch_bounds__(512, 4)
void lstm_fused(const u16* __restrict__ whh0f, const u16* __restrict__ wih1f,
                const u16* __restrict__ whh1f, const float* __restrict__ w_ih0,
                const float* __restrict__ b_ih0, const float* __restrict__ b_hh0,
                const float* __restrict__ b_ih1, const float* __restrict__ b_hh1,
                const float* __restrict__ obs, u16* __restrict__ emb)
{
  __shared__ u16 h0s[32 * LSTR];
  __shared__ u16 h1s[32 * LSTR];
  __shared__ float c1ls[32 * 256];
  __shared__ float obs_s[512];
  const int tid = threadIdx.x;
  const int lane = tid & 63, w = tid >> 6;
  const int col = lane & 31, hi = lane >> 5;
  const int r0 = blockIdx.x * 32;
  obs_s[tid] = obs[(size_t)r0 * 16 + tid];

  float bs0[4], bs1[4], xw0[4], xw1[4];
#pragma unroll
  for (int g = 0; g < 4; ++g) {
    const int cg = g*256 + w*32 + col;
    bs0[g] = b_ih0[cg] + b_hh0[cg];
    bs1[g] = b_ih1[cg] + b_hh1[cg];
    xw0[g] = w_ih0[2*cg];
    xw1[g] = w_ih0[2*cg + 1];
  }
  float c0v[16];
#pragma unroll
  for (int r = 0; r < 16; ++r) c0v[r] = 0.f;

  f32x16 za;
#pragma unroll
  for (int i = 0; i < 16; ++i) za[i] = 0.f;

  __syncthreads();

  for (int t = 0; t < 8; ++t) {
    f32x16 acc[4];
#pragma unroll
    for (int g = 0; g < 4; ++g) acc[g] = za;
    if (t > 0) {
      // P1: layer-0 recurrence
#pragma unroll 4
      for (int ks = 0; ks < 16; ++ks) {
        s16x8 a = *(const s16x8*)(h0s + col*LSTR + ks*16 + hi*8);
#pragma unroll
        for (int g = 0; g < 4; ++g) {
          s16x8 b = *(const s16x8*)(whh0f + ((size_t)((g*8 + w)*16 + ks)*64 + lane)*8);
          acc[g] = __builtin_amdgcn_mfma_f32_32x32x16_bf16(a, b, acc[g], 0, 0, 0);
        }
      }
    }
    __syncthreads();          // P1 reads of h0s done
    // E0: layer-0 cell update -> h0s
#pragma unroll
    for (int r = 0; r < 16; ++r) {
      const int row = (r&3) + 8*(r>>2) + 4*hi;
      const float x0 = obs_s[row*16 + 2*t], x1 = obs_s[row*16 + 2*t + 1];
      const float gi = acc[0][r] + bs0[0] + x0*xw0[0] + x1*xw1[0];
      const float gf = acc[1][r] + bs0[1] + x0*xw0[1] + x1*xw1[1];
      const float gg = acc[2][r] + bs0[2] + x0*xw0[2] + x1*xw1[2];
      const float go = acc[3][r] + bs0[3] + x0*xw0[3] + x1*xw1[3];
      const float cn = sigm(gf)*c0v[r] + sigm(gi)*tanhfast(gg);
      c0v[r] = cn;
      h0s[row*LSTR + w*32 + col] = f2bf(sigm(go)*tanhfast(cn));
    }
    __syncthreads();          // h0s new visible
    // P2: layer-1 gates = h0_new @ wih1 (+ h1_old @ whh1)
#pragma unroll
    for (int g = 0; g < 4; ++g) acc[g] = za;
    if (t > 0) {
#pragma unroll 2
      for (int ks = 0; ks < 16; ++ks) {
        s16x8 a0 = *(const s16x8*)(h0s + col*LSTR + ks*16 + hi*8);
        s16x8 a1 = *(const s16x8*)(h1s + col*LSTR + ks*16 + hi*8);
#pragma unroll
        for (int g = 0; g < 4; ++g) {
          const size_t fo = ((size_t)((g*8 + w)*16 + ks)*64 + lane)*8;
          s16x8 b0 = *(const s16x8*)(wih1f + fo);
          acc[g] = __builtin_amdgcn_mfma_f32_32x32x16_bf16(a0, b0, acc[g], 0, 0, 0);
          s16x8 b1 = *(const s16x8*)(whh1f + fo);
          acc[g] = __builtin_amdgcn_mfma_f32_32x32x16_bf16(a1, b1, acc[g], 0, 0, 0);
        }
      }
    } else {
#pragma unroll 4
      for (int ks = 0; ks < 16; ++ks) {
        s16x8 a0 = *(const s16x8*)(h0s + col*LSTR + ks*16 + hi*8);
#pragma unroll
        for (int g = 0; g < 4; ++g) {
          s16x8 b0 = *(const s16x8*)(wih1f + ((size_t)((g*8 + w)*16 + ks)*64 + lane)*8);
          acc[g] = __builtin_amdgcn_mfma_f32_32x32x16_bf16(a0, b0, acc[g], 0, 0, 0);
        }
      }
    }
    __syncthreads();          // P2 reads of h1s done
    // E1: layer-1 cell update (c1 in LDS) -> h1s
#pragma unroll
    for (int r = 0; r < 16; ++r) {
      const int row = (r&3) + 8*(r>>2) + 4*hi;
      const int e = w*32 + col;
      const float gi = acc[0][r] + bs1[0];
      const float gf = acc[1][r] + bs1[1];
      const float gg = acc[2][r] + bs1[2];
      const float go = acc[3][r] + bs1[3];
      const float cold = (t > 0) ? c1ls[row*256 + e] : 0.f;
      const float cn = sigm(gf)*cold + sigm(gi)*tanhfast(gg);
      c1ls[row*256 + e] = cn;
      h1s[row*LSTR + e] = f2bf(sigm(go)*tanhfast(cn));
    }
    __syncthreads();          // h1s new visible for next t
  }
  // emb = h1[7]
#pragma unroll
  for (int kk = 0; kk < 2; ++kk) {
    const int gi2 = tid + kk*512;
    const int row = gi2 >> 5, grp = gi2 & 31;
    *(s16x8*)(emb + (size_t)(r0 + row)*256 + grp*8) = *(const s16x8*)(h1s + row*LSTR + grp*8);
  }
}

// ---------------------------------------------------------------------------
// mode_stack: 1024 thr (16 waves), 64 rows x one mode. grid (128, 20).
// Wave w: col-tile ct=w&7, row-tile rh=w>>3. acc[1] per GEMM.
// LDS 68KB -> 2 independent blocks/CU (8 waves/SIMD).
__device__ __forceinline__ void gemm64(const u16* As, const u16* __restrict__ Bf,
                                       f32x16& acc, int ct, int rh, int lane)
{
  const int col = lane & 31, hi = lane >> 5;
#pragma unroll 8
  for (int ks = 0; ks < 16; ++ks) {
    s16x8 b = *(const s16x8*)(Bf + ((size_t)(ct*16 + ks)*64 + lane)*8);
    s16x8 a = *(const s16x8*)(As + (rh*32 + col)*LSTR + ks*16 + hi*8);
    acc = __builtin_amdgcn_mfma_f32_32x32x16_bf16(a, b, acc, 0, 0, 0);
  }
}

__device__ __forceinline__ void gemm_ffn2_64(const u16* As, const u16* __restrict__ Bf,
                                             f32x16& acc, int c4, int ct, int rh, int lane)
{
  const int col = lane & 31, hi = lane >> 5;
#pragma unroll 8
  for (int ks = 0; ks < 16; ++ks) {
    s16x8 b = *(const s16x8*)(Bf + ((size_t)(ct*64 + c4*16 + ks)*64 + lane)*8);
    s16x8 a = *(const s16x8*)(As + (rh*32 + col)*LSTR + ks*16 + hi*8);
    acc = __builtin_amdgcn_mfma_f32_32x32x16_bf16(a, b, acc, 0, 0, 0);
  }
}

template<int ACT>
__device__ __forceinline__ void epi_store64(f32x16 acc, const float* __restrict__ bias,
                                            u16* Ys, int ct, int rh, int lane)
{
  const int col = lane & 31, hi = lane >> 5, cg = ct*32 + col;
  const float bv = bias[cg];
#pragma unroll
  for (int r = 0; r < 16; ++r) {
    float v = acc[r] + bv;
    if (ACT == 1) v = fmaxf(v, 0.f);
    else if (ACT == 2) v = eluf(v);
    const int row = rh*32 + (r&3) + 8*(r>>2) + 4*hi;
    Ys[row*LSTR + cg] = f2bf(v);
  }
}

__device__ __forceinline__ void lnpass64(const u16* In, u16* Out,
    const float* __restrict__ g, const float* __restrict__ b, int tid)
{
  const int lane = tid & 63, w = tid >> 6;   // 16 waves x 4 rows
  f4 gv = *(const f4*)&g[lane*4];
  f4 bv = *(const f4*)&b[lane*4];
#pragma unroll
  for (int i = 0; i < 4; ++i) {
    const int row = w*4 + i;
    ushort4 uv = *(const ushort4*)(In + row*LSTR + lane*4);
    float v0 = bf2f(uv.x), v1 = bf2f(uv.y), v2 = bf2f(uv.z), v3 = bf2f(uv.w);
    float s  = v0 + v1 + v2 + v3;
    float ss = v0*v0 + v1*v1 + v2*v2 + v3*v3;
#pragma unroll
    for (int d = 1; d < 64; d <<= 1) { s += __shfl_xor(s, d); ss += __shfl_xor(ss, d); }
    const float mean = s * (1.f/256.f);
    const float rs = rsqrtf(ss * (1.f/256.f) - mean*mean + 1e-5f);
    ushort4 o;
    o.x = f2bf((v0 - mean)*rs*gv.x + bv.x);
    o.y = f2bf((v1 - mean)*rs*gv.y + bv.y);
    o.z = f2bf((v2 - mean)*rs*gv.z + bv.z);
    o.w = f2bf((v3 - mean)*rs*gv.w + bv.w);
    *(ushort4*)(Out + row*LSTR + lane*4) = o;
  }
}

__global__ __launch_bounds__(1024, 8)
void mode_stack(const u16* __restrict__ emb, const u16* __restrict__ W2cf,
  const float* __restrict__ b2c,
  const float* __restrict__ ln1_g, const float* __restrict__ ln1_b,
  const u16* __restrict__ ffn1f, const float* __restrict__ ffn_b1,
  const u16* __restrict__ ffn2f, const float* __restrict__ ffn_b2,
  const float* __restrict__ ln2_g, const float* __restrict__ ln2_b,
  const u16* __restrict__ dec1f, const float* __restrict__ dec_b1,
  const u16* __restrict__ dec2f, const float* __restrict__ dec_b2,
  const u16* __restrict__ sc1f,  const float* __restrict__ sc_b1,
  const float* __restrict__ sc_w2, const float* __restrict__ sc_b2,
  const float* __restrict__ obs, float* __restrict__ pred, float* __restrict__ score)
{
  __shared__ u16 Xs[64 * LSTR];
  __shared__ u16 Ys[64 * LSTR];
  __shared__ float obs_ls[128];
  const int tid = threadIdx.x;
  const int lane = tid & 63, w = tid >> 6;
  const int ct = w & 7, rh = w >> 3;
  const int col = lane & 31, hi = lane >> 5;
  const int r0 = blockIdx.x * 64;
  const int m  = blockIdx.y;

  f32x16 za;
#pragma unroll
  for (int i = 0; i < 16; ++i) za[i] = 0.f;

#pragma unroll
  for (int kk = 0; kk < 2; ++kk) {
    const int gi2 = tid + kk*1024;
    const int row = gi2 >> 5, grp = gi2 & 31;
    *(s16x8*)(Xs + row*LSTR + grp*8) = *(const s16x8*)(emb + (size_t)(r0 + row)*256 + grp*8);
  }
  if (tid < 128) obs_ls[tid] = obs[(size_t)(r0 + (tid >> 1))*16 + 14 + (tid & 1)];
  __syncthreads();

  { // attn-out (fused v-proj + out-proj)
    f32x16 acc = za;
    gemm64(Xs, W2cf + (size_t)m*65536, acc, ct, rh, lane);
    epi_store64<0>(acc, b2c + m*256, Ys, ct, rh, lane);
  }
  __syncthreads();
  lnpass64(Ys, Xs, ln1_g, ln1_b, tid);   // Xs = h1
  __syncthreads();

  f32x16 h2 = za;
  for (int c4 = 0; c4 < 4; ++c4) {
    f32x16 tacc = za;
    gemm64(Xs, ffn1f + (size_t)c4*65536, tacc, ct, rh, lane);
    epi_store64<1>(tacc, ffn_b1 + c4*256, Ys, ct, rh, lane);
    __syncthreads();
    gemm_ffn2_64(Ys, ffn2f, h2, c4, ct, rh, lane);
    __syncthreads();
  }
  epi_store64<0>(h2, ffn_b2, Ys, ct, rh, lane);
  __syncthreads();
  lnpass64(Ys, Xs, ln2_g, ln2_b, tid);   // Xs = mm_emb
  __syncthreads();

  f32x16 dv = za;
  for (int c2 = 0; c2 < 2; ++c2) {
    f32x16 tacc = za;
    gemm64(Xs, dec1f + (size_t)c2*65536, tacc, ct, rh, lane);
    epi_store64<2>(tacc, dec_b1 + c2*256, Ys, ct, rh, lane);
    __syncthreads();
    if (ct == 0) {   // dec2: waves 0 & 8 (one per row-tile), 32 cols (24 real)
#pragma unroll 8
      for (int ks = 0; ks < 16; ++ks) {
        s16x8 b = *(const s16x8*)(dec2f + ((size_t)(c2*16 + ks)*64 + lane)*8);
        s16x8 a = *(const s16x8*)(Ys + (rh*32 + col)*LSTR + ks*16 + hi*8);
        dv = __builtin_amdgcn_mfma_f32_32x32x16_bf16(a, b, dv, 0, 0, 0);
      }
    }
    __syncthreads();
  }
  // predictions epilogue (deltas + last_pos)
  if (ct == 0 && col < 24) {
    const float db = dec_b2[col];
#pragma unroll
    for (int r = 0; r < 16; ++r) {
      const int row = rh*32 + (r&3) + 8*(r>>2) + 4*hi;
      const float lp = obs_ls[row*2 + (col & 1)];
      pred[((size_t)(r0 + row)*20 + m)*24 + col] = dv[r] + db + lp;
    }
  }

  if (ct < 4) { // score head layer 1: 128 cols = col-tiles 0..3, both row-tiles
    f32x16 sacc = za;
    gemm64(Xs, sc1f, sacc, ct, rh, lane);
    epi_store64<2>(sacc, sc_b1, Ys, ct, rh, lane);
  }
  __syncthreads();
  { // score head layer 2: dot(128) per row; 16 waves x 4 rows
    const float scb2 = sc_b2[0];
    const float2 w2v = *(const float2*)&sc_w2[lane*2];
#pragma unroll
    for (int i = 0; i < 4; ++i) {
      const int row = w*4 + i;
      u32 pv = *(const u32*)(Ys + row*LSTR + lane*2);
      float part = bf2f((u16)(pv & 0xFFFF))*w2v.x + bf2f((u16)(pv >> 16))*w2v.y;
#pragma unroll
      for (int d = 1; d < 64; d <<= 1) part += __shfl_xor(part, d);
      if (lane == 0) score[(size_t)(r0 + row)*20 + m] = part + scb2;
    }
  }
}

// ---------------------------------------------------------------------------
extern "C" void kernel_launch(void* const* d_in, const int* in_sizes, int n_in,
                              void* d_out, int out_size, void* d_ws, size_t ws_size,
                              hipStream_t stream)
{
  (void)in_sizes; (void)n_in; (void)out_size; (void)ws_size;
  const float* obs    = (const float*)d_in[0];
  const float* w_ih0  = (const float*)d_in[1];
  const float* w_hh0  = (const float*)d_in[2];
  const float* b_ih0  = (const float*)d_in[3];
  const float* b_hh0  = (const float*)d_in[4];
  const float* w_ih1  = (const float*)d_in[5];
  const float* w_hh1  = (const float*)d_in[6];
  const float* b_ih1  = (const float*)d_in[7];
  const float* b_hh1  = (const float*)d_in[8];
  const float* ipw    = (const float*)d_in[9];
  const float* ipb    = (const float*)d_in[10];
  const float* out_w  = (const float*)d_in[11];
  const float* out_b  = (const float*)d_in[12];
  const float* ln1_g  = (const float*)d_in[13];
  const float* ln1_b  = (const float*)d_in[14];
  const float* ffn_w1 = (const float*)d_in[15];
  const float* ffn_b1 = (const float*)d_in[16];
  const float* ffn_w2 = (const float*)d_in[17];
  const float* ffn_b2 = (const float*)d_in[18];
  const float* ln2_g  = (const float*)d_in[19];
  const float* ln2_b  = (const float*)d_in[20];
  const float* dec_w1 = (const float*)d_in[21];
  const float* dec_b1 = (const float*)d_in[22];
  const float* dec_w2 = (const float*)d_in[23];
  const float* dec_b2 = (const float*)d_in[24];
  const float* sc_w1  = (const float*)d_in[25];
  const float* sc_b1  = (const float*)d_in[26];
  const float* sc_w2  = (const float*)d_in[27];
  const float* sc_b2  = (const float*)d_in[28];

  float* outp   = (float*)d_out;
  float* pred   = outp;
  float* scoreo = outp + (size_t)8192*20*24;

  // workspace layout
  float* wsf   = (float*)d_ws;
  float* W2c   = wsf;                         // 1310720 f32
  float* b2cp  = wsf + 1310720;               // 5120 f32
  u16*   wsh   = (u16*)(wsf + 1315840);       // 16B-aligned
  u16* whh0f = wsh + 0;
  u16* wih1f = wsh + 262144;
  u16* whh1f = wsh + 524288;
  u16* W2cf  = wsh + 786432;
  u16* ffn1f = wsh + 2097152;
  u16* ffn2f = wsh + 2359296;
  u16* dec1f = wsh + 2621440;
  u16* dec2f = wsh + 2752512;
  u16* sc1f  = wsh + 2768896;
  u16* emb   = wsh + 2801664;                 // 8192*256 bf16

  w2c_kernel<<<dim3(16, 20), 256, 0, stream>>>(out_w, ipw, W2c);
  b2c_kernel<<<20, 256, 0, stream>>>(out_w, out_b, ipb, b2cp);
  wcvt_all<<<1368, 256, 0, stream>>>(w_hh0, w_ih1, w_hh1, W2c, ffn_w1, ffn_w2,
                                     dec_w1, dec_w2, sc_w1, wsh);
  lstm_fused<<<256, 512, 0, stream>>>(whh0f, wih1f, whh1f, w_ih0, b_ih0, b_hh0,
                                      b_ih1, b_hh1, obs, emb);
  mode_stack<<<dim3(128, 20), 1024, 0, stream>>>(emb, W2cf, b2cp,
      ln1_g, ln1_b, ffn1f, ffn_b1, ffn2f, ffn_b2, ln2_g, ln2_b,
      dec1f, dec_b1, dec2f, dec_b2, sc1f, sc_b1, sc_w2, sc_b2,
      obs, pred, scoreo);
}

// Round 7
// 776.241 us; speedup vs baseline: 1.7467x; 1.7467x over previous
//
#include <hip/hip_runtime.h>
#include <math.h>

// PredictorNoEgo: B=8192 T=8 E=256 M=20 FS=12
// Algebra: softmax over size-1 axis == 1 => ctx == v (q,k dead);
//          attn_out = emb @ (out_w[m] @ Wv[m])^T + (out_w[m]@bv[m] + out_b[m])
// R7:
//  - lstm: mega-phase — Gates1(t)=h0(t)@Wih1+h1(t-1)@Whh1 and next-step
//    h0(t)@Whh0 computed in ONE phase (12 MFMA streams); 2 barriers/t (was 4).
//  - mode_stack: R3 shape (512thr/64rows/acc[2], 68KB LDS -> 2 blocks/CU)
//    + s_setprio around MFMA. NOTE R6 lesson: launch_bounds waves/EU > 4
//    forces VGPR<=64 -> acc spills to scratch (791MB FETCH). Never again.

typedef float4 f4;
typedef unsigned int u32;
typedef unsigned short u16;
typedef __attribute__((ext_vector_type(16))) float f32x16;
typedef __attribute__((ext_vector_type(8)))  short s16x8;

__device__ __forceinline__ float sigm(float x){ return 1.0f/(1.0f + __expf(-x)); }
__device__ __forceinline__ float tanhfast(float x){ return 2.0f*sigm(2.0f*x) - 1.0f; }
__device__ __forceinline__ float eluf(float x){ return x > 0.f ? x : __expf(x) - 1.0f; }
__device__ __forceinline__ u16 f2bf(float x){
  u32 u = __float_as_uint(x);
  return (u16)((u + 0x7FFFu + ((u>>16)&1u)) >> 16);
}
__device__ __forceinline__ float bf2f(u16 h){ return __uint_as_float(((u32)h)<<16); }

// MFMA 32x32x16 bf16: A lane l: A[row=l&31][k=(l>>5)*8+j]; B lane l: B[k][col=l&31]
// C/D reg r: row=(r&3)+8*(r>>2)+4*(l>>5), col=l&31
// Fragment-linear W' (row-major W[C][K]): elem ((ct*(K/16)+ks)*64+l)*8+j
//   = W[ct*32+(l&31)][ks*16+(l>>5)*8+j]

#define LSTR 264  // LDS row stride in u16 (528B): 16B-aligned, bank-balanced

// ---------------------------------------------------------------------------
// W2c[m] = out_w[m] (256x256) @ in_proj_w[m,512:768,:] (256x256)   (fp32)
__global__ __launch_bounds__(256, 4)
void w2c_kernel(const float* __restrict__ out_w, const float* __restrict__ ipw,
                float* __restrict__ W2c)
{
  __shared__ float As[16][68];
  __shared__ float Bs2[16][68];
  const int tid = threadIdx.x;
  const int m = blockIdx.y;
  const int o0 = (blockIdx.x >> 2) * 64, e0 = (blockIdx.x & 3) * 64;
  const int trow = tid >> 4, tcol = tid & 15;
  const float* Ap = out_w + (size_t)m * 65536;
  const float* Bp = ipw + ((size_t)m * 768 + 512) * 256;
  float acc[16];
#pragma unroll
  for (int z = 0; z < 16; ++z) acc[z] = 0.f;
  for (int kb = 0; kb < 256; kb += 16) {
    { int row = tid >> 2, ko = (tid & 3) * 4;
      f4 v = *(const f4*)(Ap + (size_t)(o0+row)*256 + kb + ko);
      As[ko+0][row]=v.x; As[ko+1][row]=v.y; As[ko+2][row]=v.z; As[ko+3][row]=v.w; }
    { int k = tid >> 4, eo = (tid & 15) * 4;
      *(f4*)&Bs2[k][eo] = *(const f4*)(Bp + (size_t)(kb+k)*256 + e0 + eo); }
    __syncthreads();
#pragma unroll
    for (int k = 0; k < 16; ++k) {
      f4 a4 = *(const f4*)&As[k][trow*4];
      f4 b4 = *(const f4*)&Bs2[k][tcol*4];
      acc[0]+=a4.x*b4.x; acc[1]+=a4.x*b4.y; acc[2]+=a4.x*b4.z; acc[3]+=a4.x*b4.w;
      acc[4]+=a4.y*b4.x; acc[5]+=a4.y*b4.y; acc[6]+=a4.y*b4.z; acc[7]+=a4.y*b4.w;
      acc[8]+=a4.z*b4.x; acc[9]+=a4.z*b4.y; acc[10]+=a4.z*b4.z; acc[11]+=a4.z*b4.w;
      acc[12]+=a4.w*b4.x; acc[13]+=a4.w*b4.y; acc[14]+=a4.w*b4.z; acc[15]+=a4.w*b4.w;
    }
    __syncthreads();
  }
#pragma unroll
  for (int i = 0; i < 4; ++i)
    *(f4*)&W2c[((size_t)m*256 + o0 + trow*4 + i)*256 + e0 + tcol*4] =
        make_float4(acc[i*4+0], acc[i*4+1], acc[i*4+2], acc[i*4+3]);
}

__global__ void b2c_kernel(const float* __restrict__ out_w, const float* __restrict__ out_b,
                           const float* __restrict__ ipb, float* __restrict__ b2c)
{
  __shared__ float pb[256];
  const int m = blockIdx.x, o = threadIdx.x;
  pb[o] = ipb[(size_t)m*768 + 512 + o];
  __syncthreads();
  const float* wr = out_w + ((size_t)m*256 + o)*256;
  float acc = out_b[(size_t)m*256 + o];
  for (int f = 0; f < 256; f += 4) {
    f4 w = *(const f4*)&wr[f];
    acc += w.x*pb[f] + w.y*pb[f+1] + w.z*pb[f+2] + w.w*pb[f+3];
  }
  b2c[(size_t)m*256 + o] = acc;
}

// ---------------------------------------------------------------------------
// f32 row-major [C][K] -> fragment-linear bf16
__device__ __forceinline__ void cvt_seg(const float* __restrict__ src, u16* __restrict__ dst,
                                        int Creal, int lognks, int g)
{
  const int l = g & 63;
  const int cks = g >> 6;
  const int ks = cks & ((1 << lognks) - 1);
  const int ct = cks >> lognks;
  const int c = ct*32 + (l & 31);
  const int K = 16 << lognks;
  const int k = ks*16 + ((l >> 5) * 8);
  s16x8 r;
  if (c < Creal) {
    const float* s = src + (size_t)c * K + k;
    f4 v0 = *(const f4*)s;
    f4 v1 = *(const f4*)(s + 4);
    r[0]=(short)f2bf(v0.x); r[1]=(short)f2bf(v0.y); r[2]=(short)f2bf(v0.z); r[3]=(short)f2bf(v0.w);
    r[4]=(short)f2bf(v1.x); r[5]=(short)f2bf(v1.y); r[6]=(short)f2bf(v1.z); r[7]=(short)f2bf(v1.w);
  } else {
#pragma unroll
    for (int j = 0; j < 8; ++j) r[j] = 0;
  }
  *(s16x8*)(dst + (size_t)g * 8) = r;
}

__global__ __launch_bounds__(256)
void wcvt_all(const float* __restrict__ whh0, const float* __restrict__ wih1,
              const float* __restrict__ whh1, const float* __restrict__ W2c,
              const float* __restrict__ ffn1, const float* __restrict__ ffn2,
              const float* __restrict__ dec1, const float* __restrict__ dec2,
              const float* __restrict__ sc1,  u16* __restrict__ dst)
{
  int g = blockIdx.x * 256 + threadIdx.x;
  if      (g <  32768) cvt_seg(whh0, dst + 0,       1024, 4, g);
  else if (g <  65536) cvt_seg(wih1, dst + 262144,  1024, 4, g - 32768);
  else if (g <  98304) cvt_seg(whh1, dst + 524288,  1024, 4, g - 65536);
  else if (g < 262144) cvt_seg(W2c,  dst + 786432,  5120, 4, g - 98304);
  else if (g < 294912) cvt_seg(ffn1, dst + 2097152, 1024, 4, g - 262144);
  else if (g < 327680) cvt_seg(ffn2, dst + 2359296,  256, 6, g - 294912);
  else if (g < 344064) cvt_seg(dec1, dst + 2621440,  512, 4, g - 327680);
  else if (g < 346112) cvt_seg(dec2, dst + 2752512,   24, 5, g - 344064);
  else if (g < 350208) cvt_seg(sc1,  dst + 2768896,  128, 4, g - 346112);
}

// ---------------------------------------------------------------------------
// Fused LSTM, mega-phase pipeline. 256 blocks x 32 rows, 512 thr (8 waves).
// Loop invariant at PHASE(t): h0s = h0(t), h1s = h1(t-1) (t>0).
// PHASE(t): aL1 = h0(t)@Wih1 [+ h1(t-1)@Whh1], aL0 = h0(t)@Whh0.
// EPI(t):   E1(t) -> h1s ; E0(t+1) from aL0 + x(t+1) -> h0s.
// 2 barriers per t (was 4). 12 MFMA streams per ks in the main phase.
__global__ __launch_bounds__(512, 2)
void lstm_fused(const u16* __restrict__ whh0f, const u16* __restrict__ wih1f,
                const u16* __restrict__ whh1f, const float* __restrict__ w_ih0,
                const float* __restrict__ b_ih0, const float* __restrict__ b_hh0,
                const float* __restrict__ b_ih1, const float* __restrict__ b_hh1,
                const float* __restrict__ obs, u16* __restrict__ emb)
{
  __shared__ u16 h0s[32 * LSTR];
  __shared__ u16 h1s[32 * LSTR];
  __shared__ float obs_s[512];
  const int tid = threadIdx.x;
  const int lane = tid & 63, w = tid >> 6;
  const int col = lane & 31, hi = lane >> 5;
  const int r0 = blockIdx.x * 32;
  obs_s[tid] = obs[(size_t)r0 * 16 + tid];

  float bs0[4], bs1[4], xw0[4], xw1[4];
#pragma unroll
  for (int g = 0; g < 4; ++g) {
    const int cg = g*256 + w*32 + col;
    bs0[g] = b_ih0[cg] + b_hh0[cg];
    bs1[g] = b_ih1[cg] + b_hh1[cg];
    xw0[g] = w_ih0[2*cg];
    xw1[g] = w_ih0[2*cg + 1];
  }
  float c0v[16], c1v[16];
#pragma unroll
  for (int r = 0; r < 16; ++r) { c0v[r] = 0.f; c1v[r] = 0.f; }

  f32x16 za;
#pragma unroll
  for (int i = 0; i < 16; ++i) za[i] = 0.f;

  __syncthreads();
  // E0(0): h0(0) from x(0) only (c0 = 0)
#pragma unroll
  for (int r = 0; r < 16; ++r) {
    const int row = (r&3) + 8*(r>>2) + 4*hi;
    const float x0 = obs_s[row*16], x1 = obs_s[row*16 + 1];
    const float gi = bs0[0] + x0*xw0[0] + x1*xw1[0];
    const float gg = bs0[2] + x0*xw0[2] + x1*xw1[2];
    const float go = bs0[3] + x0*xw0[3] + x1*xw1[3];
    const float cn = sigm(gi)*tanhfast(gg);
    c0v[r] = cn;
    h0s[row*LSTR + w*32 + col] = f2bf(sigm(go)*tanhfast(cn));
  }
  __syncthreads();

  for (int t = 0; t < 8; ++t) {
    f32x16 aL1[4], aL0[4];
#pragma unroll
    for (int g = 0; g < 4; ++g) { aL1[g] = za; aL0[g] = za; }
    if (t > 0) {
#pragma unroll 2
      for (int ks = 0; ks < 16; ++ks) {
        s16x8 a0 = *(const s16x8*)(h0s + col*LSTR + ks*16 + hi*8);
        s16x8 a1 = *(const s16x8*)(h1s + col*LSTR + ks*16 + hi*8);
#pragma unroll
        for (int g = 0; g < 4; ++g) {
          const size_t fo = ((size_t)((g*8 + w)*16 + ks)*64 + lane)*8;
          s16x8 b0 = *(const s16x8*)(wih1f + fo);
          aL1[g] = __builtin_amdgcn_mfma_f32_32x32x16_bf16(a0, b0, aL1[g], 0, 0, 0);
          s16x8 b1 = *(const s16x8*)(whh1f + fo);
          aL1[g] = __builtin_amdgcn_mfma_f32_32x32x16_bf16(a1, b1, aL1[g], 0, 0, 0);
          s16x8 b2 = *(const s16x8*)(whh0f + fo);
          aL0[g] = __builtin_amdgcn_mfma_f32_32x32x16_bf16(a0, b2, aL0[g], 0, 0, 0);
        }
      }
    } else {
#pragma unroll 2
      for (int ks = 0; ks < 16; ++ks) {
        s16x8 a0 = *(const s16x8*)(h0s + col*LSTR + ks*16 + hi*8);
#pragma unroll
        for (int g = 0; g < 4; ++g) {
          const size_t fo = ((size_t)((g*8 + w)*16 + ks)*64 + lane)*8;
          s16x8 b0 = *(const s16x8*)(wih1f + fo);
          aL1[g] = __builtin_amdgcn_mfma_f32_32x32x16_bf16(a0, b0, aL1[g], 0, 0, 0);
          s16x8 b2 = *(const s16x8*)(whh0f + fo);
          aL0[g] = __builtin_amdgcn_mfma_f32_32x32x16_bf16(a0, b2, aL0[g], 0, 0, 0);
        }
      }
    }
    __syncthreads();          // phase reads of h0s/h1s done
    // E1(t): layer-1 cell update -> h1s
#pragma unroll
    for (int r = 0; r < 16; ++r) {
      const int row = (r&3) + 8*(r>>2) + 4*hi;
      const float gi = aL1[0][r] + bs1[0];
      const float gf = aL1[1][r] + bs1[1];
      const float gg = aL1[2][r] + bs1[2];
      const float go = aL1[3][r] + bs1[3];
      const float cn = sigm(gf)*c1v[r] + sigm(gi)*tanhfast(gg);
      c1v[r] = cn;
      h1s[row*LSTR + w*32 + col] = f2bf(sigm(go)*tanhfast(cn));
    }
    // E0(t+1): layer-0 cell update -> h0s
    if (t < 7) {
#pragma unroll
      for (int r = 0; r < 16; ++r) {
        const int row = (r&3) + 8*(r>>2) + 4*hi;
        const float x0 = obs_s[row*16 + 2*(t+1)], x1 = obs_s[row*16 + 2*(t+1) + 1];
        const float gi = aL0[0][r] + bs0[0] + x0*xw0[0] + x1*xw1[0];
        const float gf = aL0[1][r] + bs0[1] + x0*xw0[1] + x1*xw1[1];
        const float gg = aL0[2][r] + bs0[2] + x0*xw0[2] + x1*xw1[2];
        const float go = aL0[3][r] + bs0[3] + x0*xw0[3] + x1*xw1[3];
        const float cn = sigm(gf)*c0v[r] + sigm(gi)*tanhfast(gg);
        c0v[r] = cn;
        h0s[row*LSTR + w*32 + col] = f2bf(sigm(go)*tanhfast(cn));
      }
    }
    __syncthreads();          // new h0s/h1s visible
  }
  // emb = h1(7)
#pragma unroll
  for (int kk = 0; kk < 2; ++kk) {
    const int gi2 = tid + kk*512;
    const int row = gi2 >> 5, grp = gi2 & 31;
    *(s16x8*)(emb + (size_t)(r0 + row)*256 + grp*8) = *(const s16x8*)(h1s + row*LSTR + grp*8);
  }
}

// ---------------------------------------------------------------------------
// mode_stack: 512 thr (8 waves), 64 rows x one mode. grid (128, 20).
// Wave w = col-tile ct=w, both row-tiles: acc[2]. LDS 68KB -> 2 blocks/CU.
__device__ __forceinline__ void gemmP(const u16* As, const u16* __restrict__ Bf,
                                      f32x16 acc[2], int ct, int lane)
{
  const int col = lane & 31, hi = lane >> 5;
  __builtin_amdgcn_s_setprio(1);
#pragma unroll 4
  for (int ks = 0; ks < 16; ++ks) {
    s16x8 b = *(const s16x8*)(Bf + ((size_t)(ct*16 + ks)*64 + lane)*8);
#pragma unroll
    for (int i = 0; i < 2; ++i) {
      s16x8 a = *(const s16x8*)(As + (i*32 + col)*LSTR + ks*16 + hi*8);
      acc[i] = __builtin_amdgcn_mfma_f32_32x32x16_bf16(a, b, acc[i], 0, 0, 0);
    }
  }
  __builtin_amdgcn_s_setprio(0);
}

__device__ __forceinline__ void gemmF2(const u16* As, const u16* __restrict__ Bf,
                                       f32x16 acc[2], int c4, int ct, int lane)
{
  const int col = lane & 31, hi = lane >> 5;
  __builtin_amdgcn_s_setprio(1);
#pragma unroll 4
  for (int ks = 0; ks < 16; ++ks) {
    s16x8 b = *(const s16x8*)(Bf + ((size_t)(ct*64 + c4*16 + ks)*64 + lane)*8);
#pragma unroll
    for (int i = 0; i < 2; ++i) {
      s16x8 a = *(const s16x8*)(As + (i*32 + col)*LSTR + ks*16 + hi*8);
      acc[i] = __builtin_amdgcn_mfma_f32_32x32x16_bf16(a, b, acc[i], 0, 0, 0);
    }
  }
  __builtin_amdgcn_s_setprio(0);
}

template<int ACT>
__device__ __forceinline__ void epiP(f32x16 acc[2], const float* __restrict__ bias,
                                     u16* Ys, int ct, int lane)
{
  const int col = lane & 31, hi = lane >> 5, cg = ct*32 + col;
  const float bv = bias[cg];
#pragma unroll
  for (int i = 0; i < 2; ++i)
#pragma unroll
    for (int r = 0; r < 16; ++r) {
      float v = acc[i][r] + bv;
      if (ACT == 1) v = fmaxf(v, 0.f);
      else if (ACT == 2) v = eluf(v);
      const int row = i*32 + (r&3) + 8*(r>>2) + 4*hi;
      Ys[row*LSTR + cg] = f2bf(v);
    }
}

__device__ __forceinline__ void lnp(const u16* In, u16* Out,
    const float* __restrict__ g, const float* __restrict__ b, int tid)
{
  const int lane = tid & 63, w = tid >> 6;   // 8 waves x 8 rows
  f4 gv = *(const f4*)&g[lane*4];
  f4 bv = *(const f4*)&b[lane*4];
#pragma unroll
  for (int i = 0; i < 8; ++i) {
    const int row = w*8 + i;
    ushort4 uv = *(const ushort4*)(In + row*LSTR + lane*4);
    float v0 = bf2f(uv.x), v1 = bf2f(uv.y), v2 = bf2f(uv.z), v3 = bf2f(uv.w);
    float s  = v0 + v1 + v2 + v3;
    float ss = v0*v0 + v1*v1 + v2*v2 + v3*v3;
#pragma unroll
    for (int d = 1; d < 64; d <<= 1) { s += __shfl_xor(s, d); ss += __shfl_xor(ss, d); }
    const float mean = s * (1.f/256.f);
    const float rs = rsqrtf(ss * (1.f/256.f) - mean*mean + 1e-5f);
    ushort4 o;
    o.x = f2bf((v0 - mean)*rs*gv.x + bv.x);
    o.y = f2bf((v1 - mean)*rs*gv.y + bv.y);
    o.z = f2bf((v2 - mean)*rs*gv.z + bv.z);
    o.w = f2bf((v3 - mean)*rs*gv.w + bv.w);
    *(ushort4*)(Out + row*LSTR + lane*4) = o;
  }
}

__global__ __launch_bounds__(512, 4)
void mode_stack(const u16* __restrict__ emb, const u16* __restrict__ W2cf,
  const float* __restrict__ b2c,
  const float* __restrict__ ln1_g, const float* __restrict__ ln1_b,
  const u16* __restrict__ ffn1f, const float* __restrict__ ffn_b1,
  const u16* __restrict__ ffn2f, const float* __restrict__ ffn_b2,
  const float* __restrict__ ln2_g, const float* __restrict__ ln2_b,
  const u16* __restrict__ dec1f, const float* __restrict__ dec_b1,
  const u16* __restrict__ dec2f, const float* __restrict__ dec_b2,
  const u16* __restrict__ sc1f,  const float* __restrict__ sc_b1,
  const float* __restrict__ sc_w2, const float* __restrict__ sc_b2,
  const float* __restrict__ obs, float* __restrict__ pred, float* __restrict__ score)
{
  __shared__ u16 Xs[64 * LSTR];
  __shared__ u16 Ys[64 * LSTR];
  __shared__ float obs_ls[128];
  const int tid = threadIdx.x;
  const int lane = tid & 63, w = tid >> 6;
  const int ct = w;
  const int col = lane & 31, hi = lane >> 5;
  const int r0 = blockIdx.x * 64;
  const int m  = blockIdx.y;

  f32x16 za;
#pragma unroll
  for (int i = 0; i < 16; ++i) za[i] = 0.f;

#pragma unroll
  for (int kk = 0; kk < 4; ++kk) {
    const int gi2 = tid + kk*512;
    const int row = gi2 >> 5, grp = gi2 & 31;
    *(s16x8*)(Xs + row*LSTR + grp*8) = *(const s16x8*)(emb + (size_t)(r0 + row)*256 + grp*8);
  }
  if (tid < 128) obs_ls[tid] = obs[(size_t)(r0 + (tid >> 1))*16 + 14 + (tid & 1)];
  __syncthreads();

  { // attn-out (fused v-proj + out-proj)
    f32x16 acc[2]; acc[0] = za; acc[1] = za;
    gemmP(Xs, W2cf + (size_t)m*65536, acc, ct, lane);
    epiP<0>(acc, b2c + m*256, Ys, ct, lane);
  }
  __syncthreads();
  lnp(Ys, Xs, ln1_g, ln1_b, tid);   // Xs = h1
  __syncthreads();

  f32x16 h2[2]; h2[0] = za; h2[1] = za;
  for (int c4 = 0; c4 < 4; ++c4) {
    f32x16 tacc[2]; tacc[0] = za; tacc[1] = za;
    gemmP(Xs, ffn1f + (size_t)c4*65536, tacc, ct, lane);
    epiP<1>(tacc, ffn_b1 + c4*256, Ys, ct, lane);
    __syncthreads();
    gemmF2(Ys, ffn2f, h2, c4, ct, lane);
    __syncthreads();
  }
  epiP<0>(h2, ffn_b2, Ys, ct, lane);
  __syncthreads();
  lnp(Ys, Xs, ln2_g, ln2_b, tid);   // Xs = mm_emb
  __syncthreads();

  f32x16 dv[2]; dv[0] = za; dv[1] = za;
  for (int c2 = 0; c2 < 2; ++c2) {
    f32x16 tacc[2]; tacc[0] = za; tacc[1] = za;
    gemmP(Xs, dec1f + (size_t)c2*65536, tacc, ct, lane);
    epiP<2>(tacc, dec_b1 + c2*256, Ys, ct, lane);
    __syncthreads();
    if (w == 0) {   // dec2: wave 0, both row-tiles, 32 cols (24 real)
#pragma unroll 4
      for (int ks = 0; ks < 16; ++ks) {
        s16x8 b = *(const s16x8*)(dec2f + ((size_t)(c2*16 + ks)*64 + lane)*8);
#pragma unroll
        for (int i = 0; i < 2; ++i) {
          s16x8 a = *(const s16x8*)(Ys + (i*32 + col)*LSTR + ks*16 + hi*8);
          dv[i] = __builtin_amdgcn_mfma_f32_32x32x16_bf16(a, b, dv[i], 0, 0, 0);
        }
      }
    }
    __syncthreads();
  }
  // predictions epilogue (deltas + last_pos)
  if (w == 0 && col < 24) {
    const float db = dec_b2[col];
#pragma unroll
    for (int i = 0; i < 2; ++i)
#pragma unroll
      for (int r = 0; r < 16; ++r) {
        const int row = i*32 + (r&3) + 8*(r>>2) + 4*hi;
        const float lp = obs_ls[row*2 + (col & 1)];
        pred[((size_t)(r0 + row)*20 + m)*24 + col] = dv[i][r] + db + lp;
      }
  }

  if (w < 4) { // score head layer 1: 128 cols = col-tiles 0..3, both row-tiles
    f32x16 sacc[2]; sacc[0] = za; sacc[1] = za;
    gemmP(Xs, sc1f, sacc, ct, lane);
    epiP<2>(sacc, sc_b1, Ys, ct, lane);
  }
  __syncthreads();
  { // score head layer 2: dot(128) per row; 8 waves x 8 rows
    const float scb2 = sc_b2[0];
    const float2 w2v = *(const float2*)&sc_w2[lane*2];
#pragma unroll
    for (int i = 0; i < 8; ++i) {
      const int row = w*8 + i;
      u32 pv = *(const u32*)(Ys + row*LSTR + lane*2);
      float part = bf2f((u16)(pv & 0xFFFF))*w2v.x + bf2f((u16)(pv >> 16))*w2v.y;
#pragma unroll
      for (int d = 1; d < 64; d <<= 1) part += __shfl_xor(part, d);
      if (lane == 0) score[(size_t)(r0 + row)*20 + m] = part + scb2;
    }
  }
}

// ---------------------------------------------------------------------------
extern "C" void kernel_launch(void* const* d_in, const int* in_sizes, int n_in,
                              void* d_out, int out_size, void* d_ws, size_t ws_size,
                              hipStream_t stream)
{
  (void)in_sizes; (void)n_in; (void)out_size; (void)ws_size;
  const float* obs    = (const float*)d_in[0];
  const float* w_ih0  = (const float*)d_in[1];
  const float* w_hh0  = (const float*)d_in[2];
  const float* b_ih0  = (const float*)d_in[3];
  const float* b_hh0  = (const float*)d_in[4];
  const float* w_ih1  = (const float*)d_in[5];
  const float* w_hh1  = (const float*)d_in[6];
  const float* b_ih1  = (const float*)d_in[7];
  const float* b_hh1  = (const float*)d_in[8];
  const float* ipw    = (const float*)d_in[9];
  const float* ipb    = (const float*)d_in[10];
  const float* out_w  = (const float*)d_in[11];
  const float* out_b  = (const float*)d_in[12];
  const float* ln1_g  = (const float*)d_in[13];
  const float* ln1_b  = (const float*)d_in[14];
  const float* ffn_w1 = (const float*)d_in[15];
  const float* ffn_b1 = (const float*)d_in[16];
  const float* ffn_w2 = (const float*)d_in[17];
  const float* ffn_b2 = (const float*)d_in[18];
  const float* ln2_g  = (const float*)d_in[19];
  const float* ln2_b  = (const float*)d_in[20];
  const float* dec_w1 = (const float*)d_in[21];
  const float* dec_b1 = (const float*)d_in[22];
  const float* dec_w2 = (const float*)d_in[23];
  const float* dec_b2 = (const float*)d_in[24];
  const float* sc_w1  = (const float*)d_in[25];
  const float* sc_b1  = (const float*)d_in[26];
  const float* sc_w2  = (const float*)d_in[27];
  const float* sc_b2  = (const float*)d_in[28];

  float* outp   = (float*)d_out;
  float* pred   = outp;
  float* scoreo = outp + (size_t)8192*20*24;

  // workspace layout
  float* wsf   = (float*)d_ws;
  float* W2c   = wsf;                         // 1310720 f32
  float* b2cp  = wsf + 1310720;               // 5120 f32
  u16*   wsh   = (u16*)(wsf + 1315840);       // 16B-aligned
  u16* whh0f = wsh + 0;
  u16* wih1f = wsh + 262144;
  u16* whh1f = wsh + 524288;
  u16* W2cf  = wsh + 786432;
  u16* ffn1f = wsh + 2097152;
  u16* ffn2f = wsh + 2359296;
  u16* dec1f = wsh + 2621440;
  u16* dec2f = wsh + 2752512;
  u16* sc1f  = wsh + 2768896;
  u16* emb   = wsh + 2801664;                 // 8192*256 bf16

  w2c_kernel<<<dim3(16, 20), 256, 0, stream>>>(out_w, ipw, W2c);
  b2c_kernel<<<20, 256, 0, stream>>>(out_w, out_b, ipb, b2cp);
  wcvt_all<<<1368, 256, 0, stream>>>(w_hh0, w_ih1, w_hh1, W2c, ffn_w1, ffn_w2,
                                     dec_w1, dec_w2, sc_w1, wsh);
  lstm_fused<<<256, 512, 0, stream>>>(whh0f, wih1f, whh1f, w_ih0, b_ih0, b_hh0,
                                      b_ih1, b_hh1, obs, emb);
  mode_stack<<<dim3(128, 20), 512, 0, stream>>>(emb, W2cf, b2cp,
      ln1_g, ln1_b, ffn1f, ffn_b1, ffn2f, ffn_b2, ln2_g, ln2_b,
      dec1f, dec_b1, dec2f, dec_b2, sc1f, sc_b1, sc_w2, sc_b2,
      obs, pred, scoreo);
}